// Round 6
// baseline (247.491 us; speedup 1.0000x reference)
//
#include <hip/hip_runtime.h>
#include <hip/hip_bf16.h>
#include <cstdint>

#define B_ 8
#define C_ 512
#define T_ 1500
#define N_ (B_*T_)      // 12000 tokens
#define NPAD_ 12032     // 94*128
#define V_ 4096
#define K_ 100
#define BKg 64

typedef unsigned long long u64;
typedef __attribute__((ext_vector_type(8))) short short8;
typedef __attribute__((ext_vector_type(4))) float f32x4;

__device__ __forceinline__ unsigned short f2bf(float x){
    __hip_bfloat16 h = __float2bfloat16(x);
    return __builtin_bit_cast(unsigned short, h);
}
__device__ __forceinline__ unsigned short f2h(float x){
    return __builtin_bit_cast(unsigned short, (_Float16)x);
}
__device__ __forceinline__ float h2fu(unsigned v){
    return (float)__builtin_bit_cast(_Float16, (unsigned short)v);
}

__device__ __forceinline__ void gll16(const unsigned short* g, unsigned short* l){
    __builtin_amdgcn_global_load_lds(
        (const __attribute__((address_space(1))) void*)g,
        (__attribute__((address_space(3))) void*)l, 16, 0, 0);
}

// ---------------- codebook: fp32 -> bf16 + csq (fp32-exact) ----------------
__global__ __launch_bounds__(256) void cbconv_kernel(const float* __restrict__ CB,
                                                     unsigned short* __restrict__ CBh,
                                                     float* __restrict__ csq){
    int wv = threadIdx.x >> 6, lane = threadIdx.x & 63;
    int r = blockIdx.x * 4 + wv;
    const float4* p4 = (const float4*)(CB + (size_t)r * C_);
    ushort4* o4 = (ushort4*)(CBh + (size_t)r * C_);
    float s = 0.f;
    #pragma unroll
    for (int j = 0; j < 2; ++j){
        float4 v = p4[lane + j*64];
        s += v.x*v.x + v.y*v.y + v.z*v.z + v.w*v.w;
        ushort4 h; h.x = f2bf(v.x); h.y = f2bf(v.y); h.z = f2bf(v.z); h.w = f2bf(v.w);
        o4[lane + j*64] = h;
    }
    #pragma unroll
    for (int o = 32; o; o >>= 1) s += __shfl_down(s, o, 64);
    if (lane == 0) csq[r] = s;
}

// ---------------- student: (B,C,T) fp32 -> embT bf16 (N,C) + esq partials ----------------
__global__ __launch_bounds__(256) void transpose_conv_kernel(const float* __restrict__ S,
                                                             unsigned short* __restrict__ embT,
                                                             float* __restrict__ esq){
    __shared__ float tile[32][33];
    __shared__ float psum[8][33];
    int b  = blockIdx.z;
    int c0 = blockIdx.y * 32;
    int t0 = blockIdx.x * 32;
    int tx = threadIdx.x, ty = threadIdx.y; // 32 x 8
    #pragma unroll
    for (int r = 0; r < 4; ++r){
        int c = c0 + ty + r*8;
        int t = t0 + tx;
        tile[ty + r*8][tx] = (t < T_) ? S[((size_t)b*C_ + c)*T_ + t] : 0.f;
    }
    __syncthreads();
    float ps = 0.f;
    #pragma unroll
    for (int r = 0; r < 4; ++r){ float v = tile[ty + r*8][tx]; ps += v * v; }
    psum[ty][tx] = ps;
    #pragma unroll
    for (int r = 0; r < 4; ++r){
        int t = t0 + ty + r*8;
        int c = c0 + tx;
        if (t < T_) embT[((size_t)b*T_ + t)*C_ + c] = f2bf(tile[tx][ty + r*8]);
    }
    __syncthreads();
    if (ty == 0){
        int t = t0 + tx;
        if (t < T_){
            float s2 = 0.f;
            #pragma unroll
            for (int w = 0; w < 8; ++w) s2 += psum[w][tx];
            atomicAdd(&esq[b*T_ + t], s2);
        }
    }
}

// ---------------- bf16 MFMA GEMM -> fp16 d2 matrix ----------------
// 128x128 tile, BK=64 (16 barriers), XOR-swizzled LDS (conflict-free, gll-compatible)
__global__ __launch_bounds__(256) void gemm_d2h_kernel(
    const unsigned short* __restrict__ A, const unsigned short* __restrict__ Bm,
    const float* __restrict__ esq, const float* __restrict__ csq,
    unsigned short* __restrict__ d2h, int row_lo, int row_hi)
{
    __shared__ unsigned short As[128*BKg];
    __shared__ unsigned short Bs[128*BKg];
    int tid = threadIdx.x, lane = tid & 63, wv = tid >> 6;
    int row0 = row_lo + blockIdx.x * 128;
    int col0 = blockIdx.y * 128;

    // staging: wave wv covers rows [wv*32, wv*32+32) in 4 gll ops of 8 rows each.
    // LDS[r*64 + c] = global[r][c ^ ((r&7)*8)]  (xor over 16B chunks)
    int sr = lane >> 3;            // 0..7 row within group
    int sk = (lane & 7) * 8;       // 0..56 halves
    int skx = sk ^ (sr * 8);       // swizzled source column
    const unsigned short* Apg[4]; const unsigned short* Bpg[4];
    unsigned short* Adg[4]; unsigned short* Bdg[4];
    #pragma unroll
    for (int g = 0; g < 4; ++g){
        int r = wv*32 + g*8 + sr;
        int ar = row0 + r; ar = (ar < N_) ? ar : N_-1;
        Apg[g] = A  + (size_t)ar * C_ + skx;
        Bpg[g] = Bm + (size_t)(col0 + r) * C_ + skx;
        Adg[g] = &As[(wv*32 + g*8) * BKg];
        Bdg[g] = &Bs[(wv*32 + g*8) * BKg];
    }

    int wm = (wv >> 1) * 64, wn = (wv & 1) * 64;
    int fr = lane & 15;            // fragment row (m or n)
    int fk = (lane >> 4) * 8;      // fragment k offset within 32
    int xo = (fr & 7) * 8;         // read-side xor

    f32x4 acc[4][4];
    #pragma unroll
    for (int i = 0; i < 4; ++i)
        #pragma unroll
        for (int j = 0; j < 4; ++j) acc[i][j] = (f32x4){0.f, 0.f, 0.f, 0.f};

    for (int kt = 0; kt < C_/BKg; ++kt){
        int k0 = kt * BKg;
        #pragma unroll
        for (int g = 0; g < 4; ++g) gll16(Apg[g] + k0, Adg[g]);
        #pragma unroll
        for (int g = 0; g < 4; ++g) gll16(Bpg[g] + k0, Bdg[g]);
        __syncthreads();   // drains vmcnt: staged data visible
        #pragma unroll
        for (int kk = 0; kk < 2; ++kk){
            int fo = (fk + kk*32) ^ xo;
            short8 af[4], bf[4];
            #pragma unroll
            for (int i = 0; i < 4; ++i) af[i] = *(const short8*)&As[(wm + i*16 + fr)*BKg + fo];
            #pragma unroll
            for (int j = 0; j < 4; ++j) bf[j] = *(const short8*)&Bs[(wn + j*16 + fr)*BKg + fo];
            #pragma unroll
            for (int i = 0; i < 4; ++i)
                #pragma unroll
                for (int j = 0; j < 4; ++j)
                    acc[i][j] = __builtin_amdgcn_mfma_f32_16x16x32_bf16(af[i], bf[j], acc[i][j], 0, 0, 0);
        }
        __syncthreads();   // before overwriting the single LDS buffer
    }

    // epilogue: C/D layout col=lane&15, row=(lane>>4)*4+reg; write d2 as fp16
    int er = (lane >> 4) * 4;
    int ec = lane & 15;
    #pragma unroll
    for (int i = 0; i < 4; ++i){
        #pragma unroll
        for (int r = 0; r < 4; ++r){
            int n = row0 + wm + i*16 + er + r;
            if (n >= row_hi) continue;
            float en = esq[n];
            size_t base = (size_t)(n - row_lo) * V_;
            #pragma unroll
            for (int j = 0; j < 4; ++j){
                int v = col0 + wn + j*16 + ec;
                float d2 = fmaxf(en + csq[v] - 2.f * acc[i][j][r], 0.f);
                d2h[base + v] = f2h(d2);
            }
        }
    }
}

// ---------------- selection v5: wave/row, packed fp16-d2 keys ----------------
__global__ __launch_bounds__(256, 2) void select_kernel(const unsigned short* __restrict__ d2h,
                                                        const int* __restrict__ codes,
                                                        float2* __restrict__ pairbuf,
                                                        int row_lo, int nrows){
    int tid = threadIdx.x, lane = tid & 63, wv = tid >> 6;
    int lrow = blockIdx.x * 4 + wv;
    if (lrow >= nrows) return;               // wave-uniform, no barriers below
    int n = row_lo + lrow;
    const uint4* r4 = (const uint4*)(d2h + (size_t)lrow * V_);

    __shared__ unsigned hist[4][256] __attribute__((aligned(16)));
    __shared__ unsigned coll[4][64];
    __shared__ unsigned collcnt[4];

    // 64 fp16 keys/lane, packed 2 per reg
    unsigned p[32];
    #pragma unroll
    for (int j = 0; j < 8; ++j){
        uint4 q = r4[lane + j*64];
        p[4*j] = q.x; p[4*j+1] = q.y; p[4*j+2] = q.z; p[4*j+3] = q.w;
    }
    int code = codes[n];
    unsigned ucode = (unsigned)d2h[(size_t)lrow * V_ + code];

    // ---- fused min-key+argmin via 32-bit (key<<16)|idx, plus max key ----
    // element idx for p[m] halves: lo -> 8*lane + 512*(m>>2) + 2*(m&3), hi -> +1
    unsigned cmin = 0xFFFFFFFFu, kmax = 0u;
    #pragma unroll
    for (int m = 0; m < 32; ++m){
        unsigned idx = 8u*(unsigned)lane + 512u*(unsigned)(m>>2) + 2u*(unsigned)(m&3);
        unsigned cl_ = (p[m] << 16) | idx;
        unsigned ch_ = (p[m] & 0xFFFF0000u) | (idx + 1u);
        unsigned cc = (cl_ < ch_) ? cl_ : ch_;
        if (cc < cmin) cmin = cc;
        unsigned lo = p[m] & 0xFFFFu, hi = p[m] >> 16;
        unsigned mm = (lo > hi) ? lo : hi;
        if (mm > kmax) kmax = mm;
    }
    #pragma unroll
    for (int o = 32; o; o >>= 1){
        unsigned a = (unsigned)__shfl_xor((int)cmin, o, 64); if (a < cmin) cmin = a;
        unsigned b = (unsigned)__shfl_xor((int)kmax, o, 64); if (b > kmax) kmax = b;
    }
    unsigned umin = cmin >> 16;
    int idx0 = (int)(cmin & 0xFFFFu);
    float d0 = sqrtf(h2fu(umin));

    // ---- rank-99 threshold t (u16 key) via per-wave histogram + in-bin ballot search ----
    unsigned t;
    if (umin == kmax){
        t = umin;
    } else {
        ((uint4*)&hist[wv][0])[lane] = (uint4){0u,0u,0u,0u};
        if (lane == 0) collcnt[wv] = 0u;
        asm volatile("s_waitcnt lgkmcnt(0)" ::: "memory");
        float fmn = h2fu(umin), fmx = h2fu(kmax);
        float invw = 256.0f / (fmx - fmn);
        #pragma unroll
        for (int m = 0; m < 32; ++m){
            int b0 = (int)((h2fu(p[m] & 0xFFFFu) - fmn) * invw); b0 = (b0 > 255) ? 255 : b0;
            int b1 = (int)((h2fu(p[m] >> 16)     - fmn) * invw); b1 = (b1 > 255) ? 255 : b1;
            atomicAdd(&hist[wv][b0], 1u);
            atomicAdd(&hist[wv][b1], 1u);
        }
        asm volatile("s_waitcnt lgkmcnt(0)" ::: "memory");
        uint4 hq = ((uint4*)&hist[wv][0])[lane];
        unsigned lsum = hq.x + hq.y + hq.z + hq.w;
        unsigned inc = lsum;
        #pragma unroll
        for (int o = 1; o < 64; o <<= 1){
            unsigned y = (unsigned)__shfl_up((int)inc, o, 64);
            if (lane >= o) inc += y;
        }
        unsigned e0 = inc - lsum;
        unsigned e1 = e0 + hq.x, e2 = e1 + hq.y, e3 = e2 + hq.z, e4 = e3 + hq.w;
        int sel = -1;
        if      (e0 <= 99u && 99u < e1) sel = 0;
        else if (e1 <= 99u && 99u < e2) sel = 1;
        else if (e2 <= 99u && 99u < e3) sel = 2;
        else if (e3 <= 99u && 99u < e4) sel = 3;
        u64 bal = __ballot(sel >= 0);
        int src = __ffsll(bal) - 1;
        unsigned myBk = (unsigned)(4*lane + (sel < 0 ? 0 : sel));
        unsigned myBase = (sel == 1) ? e1 : (sel == 2) ? e2 : (sel == 3) ? e3 : e0;
        int Bk   = __shfl((int)myBk,   src, 64);
        int base = __shfl((int)myBase, src, 64);
        int rk = 99 - base;
        #pragma unroll
        for (int m = 0; m < 32; ++m){
            unsigned klo = p[m] & 0xFFFFu, khi = p[m] >> 16;
            int b0 = (int)((h2fu(klo) - fmn) * invw); b0 = (b0 > 255) ? 255 : b0;
            int b1 = (int)((h2fu(khi) - fmn) * invw); b1 = (b1 > 255) ? 255 : b1;
            if (b0 == Bk){
                unsigned pos = atomicAdd(&collcnt[wv], 1u);
                if (pos < 64u) coll[wv][pos] = klo;
            }
            if (b1 == Bk){
                unsigned pos = atomicAdd(&collcnt[wv], 1u);
                if (pos < 64u) coll[wv][pos] = khi;
            }
        }
        asm volatile("s_waitcnt lgkmcnt(0)" ::: "memory");
        unsigned bcnt = collcnt[wv];
        if (bcnt <= 64u){
            unsigned w = (lane < (int)bcnt) ? coll[wv][lane] : 0xFFFFFFFFu;
            unsigned wmn = (lane < (int)bcnt) ? w : 0xFFFFFFFFu;
            unsigned wmx = (lane < (int)bcnt) ? w : 0u;
            #pragma unroll
            for (int o = 32; o; o >>= 1){
                unsigned a = (unsigned)__shfl_xor((int)wmn, o, 64); if (a < wmn) wmn = a;
                unsigned b = (unsigned)__shfl_xor((int)wmx, o, 64); if (b > wmx) wmx = b;
            }
            unsigned P;
            if (wmn == wmx) P = wmn;
            else {
                int hb = 31 - __clz((int)(wmn ^ wmx));
                unsigned mask = (1u << (hb+1)) - 1u;
                P = wmn & ~mask;
                for (int b = hb; b >= 0; --b){
                    unsigned cand = P | (1u << b);
                    int c = __popcll(__ballot(w < cand));
                    if (c <= rk) P = cand;
                }
            }
            t = P;
        } else {
            // rare fallback: full-range bitwise search over 16-bit keys
            int hb = 31 - __clz((int)(umin ^ kmax));
            unsigned mask = (1u << (hb+1)) - 1u;
            unsigned P = umin & ~mask;
            for (int b = hb; b >= 0; --b){
                unsigned cand = P | (1u << b);
                int c = 0;
                #pragma unroll
                for (int m = 0; m < 32; ++m){
                    c += ((p[m] & 0xFFFFu) < cand) ? 1 : 0;
                    c += ((p[m] >> 16)     < cand) ? 1 : 0;
                }
                #pragma unroll
                for (int o = 32; o; o >>= 1) c += __shfl_xor(c, o, 64);
                if (c <= 99) P = cand;
            }
            t = P;
        }
    }
    float tval = sqrtf(h2fu(t));

    // ---- softmax denom over top-100 (tie multiplicity at t) ----
    float s = 0.f; int cl = 0;
    #pragma unroll
    for (int m = 0; m < 32; ++m){
        unsigned klo = p[m] & 0xFFFFu, khi = p[m] >> 16;
        if (klo < t){ s += __expf(d0 - sqrtf(h2fu(klo))); cl++; }
        if (khi < t){ s += __expf(d0 - sqrtf(h2fu(khi))); cl++; }
    }
    #pragma unroll
    for (int o = 32; o; o >>= 1){
        s += __shfl_xor(s, o, 64);
        cl += __shfl_xor(cl, o, 64);
    }
    if (lane == 0){
        float S = s + (float)(K_ - cl) * __expf(d0 - tval);
        float dcode = sqrtf(h2fu(ucode));
        if (ucode > t) S += __expf(d0 - dcode) - __expf(d0 - tval);  // include_correct swap
        float nll = dcode - d0 + __logf(S);
        pairbuf[n] = make_float2(nll, (idx0 == code) ? 1.f : 0.f);
    }
}

__global__ __launch_bounds__(1024) void finalize_kernel(const float2* __restrict__ pair,
                                                        float* __restrict__ out){
    int tid = threadIdx.x;
    float sn = 0.f, sh = 0.f;
    for (int i = tid; i < N_; i += 1024){
        float2 p = pair[i]; sn += p.x; sh += p.y;
    }
    #pragma unroll
    for (int o = 32; o; o >>= 1){ sn += __shfl_down(sn, o, 64); sh += __shfl_down(sh, o, 64); }
    __shared__ float a[16], b[16];
    int wv = tid >> 6, lane = tid & 63;
    if (lane == 0){ a[wv] = sn; b[wv] = sh; }
    __syncthreads();
    if (tid == 0){
        float L = 0.f, H = 0.f;
        #pragma unroll
        for (int i = 0; i < 16; ++i){ L += a[i]; H += b[i]; }
        out[0] = L / (float)N_;
        out[1] = H / (float)N_;   // local prediction is always candidate 0
        out[2] = H / (float)N_;
        out[3] = 1.0f;            // include_correct guarantees membership
    }
}

// ---------------- launcher ----------------
extern "C" void kernel_launch(void* const* d_in, const int* in_sizes, int n_in,
                              void* d_out, int out_size, void* d_ws, size_t ws_size,
                              hipStream_t stream){
    const float* S   = (const float*)d_in[0];
    const int* codes = (const int*)d_in[1];
    const float* CB  = (const float*)d_in[2];
    float* out = (float*)d_out;

    char* w = (char*)d_ws;
    size_t off = 0;
    unsigned short* embT = (unsigned short*)(w + off); off += (size_t)NPAD_ * C_ * 2;
    unsigned short* CBh  = (unsigned short*)(w + off); off += (size_t)V_ * C_ * 2;
    float* csq = (float*)(w + off); off += (size_t)V_ * 4;
    float* esq = (float*)(w + off); off += (size_t)N_ * 4;
    off = (off + 255) & ~(size_t)255;
    float2* pairbuf = (float2*)(w + off); off += (size_t)N_ * 8;
    unsigned short* d2buf = (unsigned short*)(w + off);

    size_t avail = (ws_size > off) ? ws_size - off : 0;
    long maxrows = (long)(avail / ((size_t)V_ * 2));
    int chunk = (maxrows >= N_) ? N_ : (int)maxrows;
    if (chunk < 4) chunk = 4;

    hipMemsetAsync(esq, 0, (size_t)N_ * 4, stream);
    hipLaunchKernelGGL(cbconv_kernel, dim3(V_/4), dim3(256), 0, stream, CB, CBh, csq);
    hipLaunchKernelGGL(transpose_conv_kernel, dim3((T_+31)/32, C_/32, B_), dim3(32, 8), 0, stream,
                       S, embT, esq);

    for (int row_lo = 0; row_lo < N_; row_lo += chunk){
        int row_hi = row_lo + chunk; if (row_hi > N_) row_hi = N_;
        int rows = row_hi - row_lo;
        hipLaunchKernelGGL(gemm_d2h_kernel, dim3((rows + 127)/128, V_/128), dim3(256), 0, stream,
                           embT, CBh, esq, csq, d2buf, row_lo, row_hi);
        hipLaunchKernelGGL(select_kernel, dim3((rows + 3)/4), dim3(256), 0, stream,
                           d2buf, codes, pairbuf, row_lo, rows);
    }
    hipLaunchKernelGGL(finalize_kernel, dim3(1), dim3(1024), 0, stream, pairbuf, out);
}

// Round 7
// 226.236 us; speedup vs baseline: 1.0940x; 1.0940x over previous
//
#include <hip/hip_runtime.h>
#include <hip/hip_bf16.h>
#include <cstdint>

#define B_ 8
#define C_ 512
#define T_ 1500
#define N_ (B_*T_)      // 12000 tokens
#define NPAD_ 12032     // 94*128
#define V_ 4096
#define K_ 100

typedef unsigned long long u64;
typedef __attribute__((ext_vector_type(8))) short short8;
typedef __attribute__((ext_vector_type(4))) float f32x4;

__device__ __forceinline__ unsigned short f2bf(float x){
    __hip_bfloat16 h = __float2bfloat16(x);
    return __builtin_bit_cast(unsigned short, h);
}
__device__ __forceinline__ unsigned short f2h(float x){
    return __builtin_bit_cast(unsigned short, (_Float16)x);
}
__device__ __forceinline__ float h2fu(unsigned v){
    return (float)__builtin_bit_cast(_Float16, (unsigned short)v);
}

__device__ __forceinline__ void gll16(const unsigned short* g, unsigned short* l){
    __builtin_amdgcn_global_load_lds(
        (const __attribute__((address_space(1))) void*)g,
        (__attribute__((address_space(3))) void*)l, 16, 0, 0);
}

// ---------------- codebook: fp32 -> bf16 + csq (fp32-exact) ----------------
__global__ __launch_bounds__(256) void cbconv_kernel(const float* __restrict__ CB,
                                                     unsigned short* __restrict__ CBh,
                                                     float* __restrict__ csq){
    int wv = threadIdx.x >> 6, lane = threadIdx.x & 63;
    int r = blockIdx.x * 4 + wv;
    const float4* p4 = (const float4*)(CB + (size_t)r * C_);
    ushort4* o4 = (ushort4*)(CBh + (size_t)r * C_);
    float s = 0.f;
    #pragma unroll
    for (int j = 0; j < 2; ++j){
        float4 v = p4[lane + j*64];
        s += v.x*v.x + v.y*v.y + v.z*v.z + v.w*v.w;
        ushort4 h; h.x = f2bf(v.x); h.y = f2bf(v.y); h.z = f2bf(v.z); h.w = f2bf(v.w);
        o4[lane + j*64] = h;
    }
    #pragma unroll
    for (int o = 32; o; o >>= 1) s += __shfl_down(s, o, 64);
    if (lane == 0) csq[r] = s;
}

// ---------------- student: (B,C,T) fp32 -> embT bf16 (N,C) + esq partials ----------------
__global__ __launch_bounds__(256) void transpose_conv_kernel(const float* __restrict__ S,
                                                             unsigned short* __restrict__ embT,
                                                             float* __restrict__ esq){
    __shared__ float tile[32][33];
    __shared__ float psum[8][33];
    int b  = blockIdx.z;
    int c0 = blockIdx.y * 32;
    int t0 = blockIdx.x * 32;
    int tx = threadIdx.x, ty = threadIdx.y; // 32 x 8
    #pragma unroll
    for (int r = 0; r < 4; ++r){
        int c = c0 + ty + r*8;
        int t = t0 + tx;
        tile[ty + r*8][tx] = (t < T_) ? S[((size_t)b*C_ + c)*T_ + t] : 0.f;
    }
    __syncthreads();
    float ps = 0.f;
    #pragma unroll
    for (int r = 0; r < 4; ++r){ float v = tile[ty + r*8][tx]; ps += v * v; }
    psum[ty][tx] = ps;
    #pragma unroll
    for (int r = 0; r < 4; ++r){
        int t = t0 + ty + r*8;
        int c = c0 + tx;
        if (t < T_) embT[((size_t)b*T_ + t)*C_ + c] = f2bf(tile[tx][ty + r*8]);
    }
    __syncthreads();
    if (ty == 0){
        int t = t0 + tx;
        if (t < T_){
            float s2 = 0.f;
            #pragma unroll
            for (int w = 0; w < 8; ++w) s2 += psum[w][tx];
            atomicAdd(&esq[b*T_ + t], s2);
        }
    }
}

// ---------------- bf16 MFMA GEMM -> fp16 d2 matrix ----------------
// BK=32 (16 KB LDS), XOR swizzle chunk^((r>>1)&3) (conflict-free), XCD-ownership remap:
// XCD x = b&7 owns column half (x&1): its 2.1 MB B-half stays L2-resident; each
// row-group's A-tile is fetched by exactly 2 XCDs.
__global__ __launch_bounds__(256) void gemm_d2h_kernel(
    const unsigned short* __restrict__ A, const unsigned short* __restrict__ Bm,
    const float* __restrict__ esq, const float* __restrict__ csq,
    unsigned short* __restrict__ d2h, int row_lo, int row_hi, int nrb)
{
    __shared__ unsigned short As[128*32];
    __shared__ unsigned short Bs[128*32];
    int tid = threadIdx.x, lane = tid & 63, wv = tid >> 6;

    // decode: b%8 -> XCD (round-robin heuristic); within-XCD sequence t
    int b = blockIdx.x;
    int xcd = b & 7, t = b >> 3;
    int ul = t >> 4, cb = t & 15;
    int u = ul * 8 + xcd;             // unit = (row-group, col-half)
    int rg = u >> 1, half = u & 1;
    if (rg >= nrb) return;
    int row0 = row_lo + rg * 128;
    int col0 = (half * 16 + cb) * 128;

    // staging: wave wv covers rows [wv*32, wv*32+32) in two gll ops of 16 rows.
    // LDS[r][c_slot] = global[r][c_slot ^ ((r>>1)&3)]  (16B chunks)
    int sr = lane >> 2;               // 0..15 row within gll group
    int skx = ((lane & 3) ^ ((sr >> 1) & 3)) * 8;   // swizzled source halves
    int ar0 = row0 + wv*32 + sr;       int ar1 = ar0 + 16;
    int ca0 = (ar0 < N_) ? ar0 : N_-1; int ca1 = (ar1 < N_) ? ar1 : N_-1;
    const unsigned short* Ap0 = A  + (size_t)ca0 * C_ + skx;
    const unsigned short* Ap1 = A  + (size_t)ca1 * C_ + skx;
    const unsigned short* Bp0 = Bm + (size_t)(col0 + wv*32 + sr) * C_ + skx;
    const unsigned short* Bp1 = Bp0 + (size_t)16 * C_;
    unsigned short* Ad0 = &As[(wv*32     ) * 32];
    unsigned short* Ad1 = &As[(wv*32 + 16) * 32];
    unsigned short* Bd0 = &Bs[(wv*32     ) * 32];
    unsigned short* Bd1 = &Bs[(wv*32 + 16) * 32];

    int wm = (wv >> 1) * 64, wn = (wv & 1) * 64;
    int fr = lane & 15;               // fragment row (m or n)
    int fk = (lane >> 4) * 8;         // fragment k chunk * 8
    int fo = fk ^ (((fr >> 1) & 3) * 8);   // read-side swizzled offset

    f32x4 acc[4][4];
    #pragma unroll
    for (int i = 0; i < 4; ++i)
        #pragma unroll
        for (int j = 0; j < 4; ++j) acc[i][j] = (f32x4){0.f, 0.f, 0.f, 0.f};

    for (int kt = 0; kt < C_/32; ++kt){
        int k0 = kt * 32;
        gll16(Ap0 + k0, Ad0);
        gll16(Ap1 + k0, Ad1);
        gll16(Bp0 + k0, Bd0);
        gll16(Bp1 + k0, Bd1);
        __syncthreads();   // drains vmcnt: staged data visible
        short8 af[4], bf[4];
        #pragma unroll
        for (int i = 0; i < 4; ++i) af[i] = *(const short8*)&As[(wm + i*16 + fr)*32 + fo];
        #pragma unroll
        for (int j = 0; j < 4; ++j) bf[j] = *(const short8*)&Bs[(wn + j*16 + fr)*32 + fo];
        #pragma unroll
        for (int i = 0; i < 4; ++i)
            #pragma unroll
            for (int j = 0; j < 4; ++j)
                acc[i][j] = __builtin_amdgcn_mfma_f32_16x16x32_bf16(af[i], bf[j], acc[i][j], 0, 0, 0);
        __syncthreads();   // before overwriting the single LDS buffer
    }

    // epilogue: C/D layout col=lane&15, row=(lane>>4)*4+reg; write d2 as fp16
    int er = (lane >> 4) * 4;
    int ec = lane & 15;
    #pragma unroll
    for (int i = 0; i < 4; ++i){
        #pragma unroll
        for (int r = 0; r < 4; ++r){
            int n = row0 + wm + i*16 + er + r;
            if (n >= row_hi) continue;
            float en = esq[n];
            size_t base = (size_t)(n - row_lo) * V_;
            #pragma unroll
            for (int j = 0; j < 4; ++j){
                int v = col0 + wn + j*16 + ec;
                float d2 = fmaxf(en + csq[v] - 2.f * acc[i][j][r], 0.f);
                d2h[base + v] = f2h(d2);
            }
        }
    }
}

// ---------------- selection v5: wave/row, packed fp16-d2 keys ----------------
__global__ __launch_bounds__(256, 2) void select_kernel(const unsigned short* __restrict__ d2h,
                                                        const int* __restrict__ codes,
                                                        float2* __restrict__ pairbuf,
                                                        int row_lo, int nrows){
    int tid = threadIdx.x, lane = tid & 63, wv = tid >> 6;
    int lrow = blockIdx.x * 4 + wv;
    if (lrow >= nrows) return;               // wave-uniform, no barriers below
    int n = row_lo + lrow;
    const uint4* r4 = (const uint4*)(d2h + (size_t)lrow * V_);

    __shared__ unsigned hist[4][256] __attribute__((aligned(16)));
    __shared__ unsigned coll[4][64];
    __shared__ unsigned collcnt[4];

    // 64 fp16 keys/lane, packed 2 per reg
    unsigned p[32];
    #pragma unroll
    for (int j = 0; j < 8; ++j){
        uint4 q = r4[lane + j*64];
        p[4*j] = q.x; p[4*j+1] = q.y; p[4*j+2] = q.z; p[4*j+3] = q.w;
    }
    int code = codes[n];
    unsigned ucode = (unsigned)d2h[(size_t)lrow * V_ + code];

    // ---- fused min-key+argmin via 32-bit (key<<16)|idx, plus max key ----
    unsigned cmin = 0xFFFFFFFFu, kmax = 0u;
    #pragma unroll
    for (int m = 0; m < 32; ++m){
        unsigned idx = 8u*(unsigned)lane + 512u*(unsigned)(m>>2) + 2u*(unsigned)(m&3);
        unsigned cl_ = (p[m] << 16) | idx;
        unsigned ch_ = (p[m] & 0xFFFF0000u) | (idx + 1u);
        unsigned cc = (cl_ < ch_) ? cl_ : ch_;
        if (cc < cmin) cmin = cc;
        unsigned lo = p[m] & 0xFFFFu, hi = p[m] >> 16;
        unsigned mm = (lo > hi) ? lo : hi;
        if (mm > kmax) kmax = mm;
    }
    #pragma unroll
    for (int o = 32; o; o >>= 1){
        unsigned a = (unsigned)__shfl_xor((int)cmin, o, 64); if (a < cmin) cmin = a;
        unsigned b = (unsigned)__shfl_xor((int)kmax, o, 64); if (b > kmax) kmax = b;
    }
    unsigned umin = cmin >> 16;
    int idx0 = (int)(cmin & 0xFFFFu);
    float d0 = sqrtf(h2fu(umin));

    // ---- rank-99 threshold t (u16 key) via per-wave histogram + in-bin ballot search ----
    unsigned t;
    if (umin == kmax){
        t = umin;
    } else {
        ((uint4*)&hist[wv][0])[lane] = (uint4){0u,0u,0u,0u};
        if (lane == 0) collcnt[wv] = 0u;
        asm volatile("s_waitcnt lgkmcnt(0)" ::: "memory");
        float fmn = h2fu(umin), fmx = h2fu(kmax);
        float invw = 256.0f / (fmx - fmn);
        #pragma unroll
        for (int m = 0; m < 32; ++m){
            int b0 = (int)((h2fu(p[m] & 0xFFFFu) - fmn) * invw); b0 = (b0 > 255) ? 255 : b0;
            int b1 = (int)((h2fu(p[m] >> 16)     - fmn) * invw); b1 = (b1 > 255) ? 255 : b1;
            atomicAdd(&hist[wv][b0], 1u);
            atomicAdd(&hist[wv][b1], 1u);
        }
        asm volatile("s_waitcnt lgkmcnt(0)" ::: "memory");
        uint4 hq = ((uint4*)&hist[wv][0])[lane];
        unsigned lsum = hq.x + hq.y + hq.z + hq.w;
        unsigned inc = lsum;
        #pragma unroll
        for (int o = 1; o < 64; o <<= 1){
            unsigned y = (unsigned)__shfl_up((int)inc, o, 64);
            if (lane >= o) inc += y;
        }
        unsigned e0 = inc - lsum;
        unsigned e1 = e0 + hq.x, e2 = e1 + hq.y, e3 = e2 + hq.z, e4 = e3 + hq.w;
        int sel = -1;
        if      (e0 <= 99u && 99u < e1) sel = 0;
        else if (e1 <= 99u && 99u < e2) sel = 1;
        else if (e2 <= 99u && 99u < e3) sel = 2;
        else if (e3 <= 99u && 99u < e4) sel = 3;
        u64 bal = __ballot(sel >= 0);
        int src = __ffsll(bal) - 1;
        unsigned myBk = (unsigned)(4*lane + (sel < 0 ? 0 : sel));
        unsigned myBase = (sel == 1) ? e1 : (sel == 2) ? e2 : (sel == 3) ? e3 : e0;
        int Bk   = __shfl((int)myBk,   src, 64);
        int base = __shfl((int)myBase, src, 64);
        int rk = 99 - base;
        #pragma unroll
        for (int m = 0; m < 32; ++m){
            unsigned klo = p[m] & 0xFFFFu, khi = p[m] >> 16;
            int b0 = (int)((h2fu(klo) - fmn) * invw); b0 = (b0 > 255) ? 255 : b0;
            int b1 = (int)((h2fu(khi) - fmn) * invw); b1 = (b1 > 255) ? 255 : b1;
            if (b0 == Bk){
                unsigned pos = atomicAdd(&collcnt[wv], 1u);
                if (pos < 64u) coll[wv][pos] = klo;
            }
            if (b1 == Bk){
                unsigned pos = atomicAdd(&collcnt[wv], 1u);
                if (pos < 64u) coll[wv][pos] = khi;
            }
        }
        asm volatile("s_waitcnt lgkmcnt(0)" ::: "memory");
        unsigned bcnt = collcnt[wv];
        if (bcnt <= 64u){
            unsigned w = (lane < (int)bcnt) ? coll[wv][lane] : 0xFFFFFFFFu;
            unsigned wmn = (lane < (int)bcnt) ? w : 0xFFFFFFFFu;
            unsigned wmx = (lane < (int)bcnt) ? w : 0u;
            #pragma unroll
            for (int o = 32; o; o >>= 1){
                unsigned a = (unsigned)__shfl_xor((int)wmn, o, 64); if (a < wmn) wmn = a;
                unsigned b = (unsigned)__shfl_xor((int)wmx, o, 64); if (b > wmx) wmx = b;
            }
            unsigned P;
            if (wmn == wmx) P = wmn;
            else {
                int hb = 31 - __clz((int)(wmn ^ wmx));
                unsigned mask = (1u << (hb+1)) - 1u;
                P = wmn & ~mask;
                for (int b = hb; b >= 0; --b){
                    unsigned cand = P | (1u << b);
                    int c = __popcll(__ballot(w < cand));
                    if (c <= rk) P = cand;
                }
            }
            t = P;
        } else {
            int hb = 31 - __clz((int)(umin ^ kmax));
            unsigned mask = (1u << (hb+1)) - 1u;
            unsigned P = umin & ~mask;
            for (int b = hb; b >= 0; --b){
                unsigned cand = P | (1u << b);
                int c = 0;
                #pragma unroll
                for (int m = 0; m < 32; ++m){
                    c += ((p[m] & 0xFFFFu) < cand) ? 1 : 0;
                    c += ((p[m] >> 16)     < cand) ? 1 : 0;
                }
                #pragma unroll
                for (int o = 32; o; o >>= 1) c += __shfl_xor(c, o, 64);
                if (c <= 99) P = cand;
            }
            t = P;
        }
    }
    float tval = sqrtf(h2fu(t));

    // ---- softmax denom over top-100 (tie multiplicity at t) ----
    float s = 0.f; int cl = 0;
    #pragma unroll
    for (int m = 0; m < 32; ++m){
        unsigned klo = p[m] & 0xFFFFu, khi = p[m] >> 16;
        if (klo < t){ s += __expf(d0 - sqrtf(h2fu(klo))); cl++; }
        if (khi < t){ s += __expf(d0 - sqrtf(h2fu(khi))); cl++; }
    }
    #pragma unroll
    for (int o = 32; o; o >>= 1){
        s += __shfl_xor(s, o, 64);
        cl += __shfl_xor(cl, o, 64);
    }
    if (lane == 0){
        float S = s + (float)(K_ - cl) * __expf(d0 - tval);
        float dcode = sqrtf(h2fu(ucode));
        if (ucode > t) S += __expf(d0 - dcode) - __expf(d0 - tval);  // include_correct swap
        float nll = dcode - d0 + __logf(S);
        pairbuf[n] = make_float2(nll, (idx0 == code) ? 1.f : 0.f);
    }
}

__global__ __launch_bounds__(1024) void finalize_kernel(const float2* __restrict__ pair,
                                                        float* __restrict__ out){
    int tid = threadIdx.x;
    float sn = 0.f, sh = 0.f;
    for (int i = tid; i < N_; i += 1024){
        float2 p = pair[i]; sn += p.x; sh += p.y;
    }
    #pragma unroll
    for (int o = 32; o; o >>= 1){ sn += __shfl_down(sn, o, 64); sh += __shfl_down(sh, o, 64); }
    __shared__ float a[16], b[16];
    int wv = tid >> 6, lane = tid & 63;
    if (lane == 0){ a[wv] = sn; b[wv] = sh; }
    __syncthreads();
    if (tid == 0){
        float L = 0.f, H = 0.f;
        #pragma unroll
        for (int i = 0; i < 16; ++i){ L += a[i]; H += b[i]; }
        out[0] = L / (float)N_;
        out[1] = H / (float)N_;   // local prediction is always candidate 0
        out[2] = H / (float)N_;
        out[3] = 1.0f;            // include_correct guarantees membership
    }
}

// ---------------- launcher ----------------
extern "C" void kernel_launch(void* const* d_in, const int* in_sizes, int n_in,
                              void* d_out, int out_size, void* d_ws, size_t ws_size,
                              hipStream_t stream){
    const float* S   = (const float*)d_in[0];
    const int* codes = (const int*)d_in[1];
    const float* CB  = (const float*)d_in[2];
    float* out = (float*)d_out;

    char* w = (char*)d_ws;
    size_t off = 0;
    unsigned short* embT = (unsigned short*)(w + off); off += (size_t)NPAD_ * C_ * 2;
    unsigned short* CBh  = (unsigned short*)(w + off); off += (size_t)V_ * C_ * 2;
    float* csq = (float*)(w + off); off += (size_t)V_ * 4;
    float* esq = (float*)(w + off); off += (size_t)N_ * 4;
    off = (off + 255) & ~(size_t)255;
    float2* pairbuf = (float2*)(w + off); off += (size_t)N_ * 8;
    unsigned short* d2buf = (unsigned short*)(w + off);

    size_t avail = (ws_size > off) ? ws_size - off : 0;
    long maxrows = (long)(avail / ((size_t)V_ * 2));
    int chunk = (maxrows >= N_) ? N_ : (int)maxrows;
    if (chunk < 4) chunk = 4;

    hipMemsetAsync(esq, 0, (size_t)N_ * 4, stream);
    hipLaunchKernelGGL(cbconv_kernel, dim3(V_/4), dim3(256), 0, stream, CB, CBh, csq);
    hipLaunchKernelGGL(transpose_conv_kernel, dim3((T_+31)/32, C_/32, B_), dim3(32, 8), 0, stream,
                       S, embT, esq);

    for (int row_lo = 0; row_lo < N_; row_lo += chunk){
        int row_hi = row_lo + chunk; if (row_hi > N_) row_hi = N_;
        int rows = row_hi - row_lo;
        int nrb = (rows + 127) / 128;
        int nrbp = (nrb + 7) & ~7;          // pad to multiple of 8 for the XCD decode
        hipLaunchKernelGGL(gemm_d2h_kernel, dim3(nrbp * 32), dim3(256), 0, stream,
                           embT, CBh, esq, csq, d2buf, row_lo, row_hi, nrb);
        hipLaunchKernelGGL(select_kernel, dim3((rows + 3)/4), dim3(256), 0, stream,
                           d2buf, codes, pairbuf, row_lo, rows);
    }
    hipLaunchKernelGGL(finalize_kernel, dim3(1), dim3(1024), 0, stream, pairbuf, out);
}